// Round 8
// baseline (1148.896 us; speedup 1.0000x reference)
//
#include <hip/hip_runtime.h>
#include <cstdint>
#include <cstddef>

typedef _Float16 f16;
typedef f16   f16x4 __attribute__((ext_vector_type(4)));
typedef f16   f16x8 __attribute__((ext_vector_type(8)));
typedef float f32x4 __attribute__((ext_vector_type(4)));

#define MFMA16x32(a, b, c) __builtin_amdgcn_mfma_f32_16x16x32_f16((a), (b), (c), 0, 0, 0)
#define MFMA16x16(a, b, c) __builtin_amdgcn_mfma_f32_16x16x16f16((a), (b), (c), 0, 0, 0)

// async global->LDS, 16B per lane; lds base must be wave-uniform
__device__ __forceinline__ void gload_lds16(const void* g, void* l) {
    __builtin_amdgcn_global_load_lds(
        (const __attribute__((address_space(1))) unsigned int*)g,
        (__attribute__((address_space(3))) unsigned int*)l, 16, 0, 0);
}

// ---------------- prep: f32 -> f16 copy-cast (8 elems/thread) ----------------
__global__ void cvt_f32_f16(const float* __restrict__ in, f16* __restrict__ out, int n8) {
    int i = blockIdx.x * blockDim.x + threadIdx.x;
    if (i >= n8) return;
    const float4 a = ((const float4*)in)[i * 2];
    const float4 b = ((const float4*)in)[i * 2 + 1];
    f16x8 o;
    o[0] = (f16)a.x; o[1] = (f16)a.y; o[2] = (f16)a.z; o[3] = (f16)a.w;
    o[4] = (f16)b.x; o[5] = (f16)b.y; o[6] = (f16)b.z; o[7] = (f16)b.w;
    *(f16x8*)(out + (size_t)i * 8) = o;
}

// ---------------- QKV projection GEMM ----------------
// q epilogue scale = 0.125 * log2(e): scores then use exp2 directly.
__global__ __launch_bounds__(256, 3)
void gemm_qkv(const f16* __restrict__ A, const f16* __restrict__ B,
              const float* __restrict__ bq, const float* __restrict__ bk,
              const float* __restrict__ bv,
              f16* __restrict__ q_sp, f16* __restrict__ k_sp, f16* __restrict__ v_sp)
{
    __shared__ f16 Al[128 * 32];
    __shared__ f16 Bl[128 * 32];
    const int tid = threadIdx.x, lane = tid & 63, w = tid >> 6;
    const int wm = w >> 1, wn = w & 1;
    const int m0 = blockIdx.y * 128, n0 = blockIdx.x * 128;
    const int l15 = lane & 15, lh = lane >> 4;

    f32x4 acc[4][4] = {};

    const int c0 = w, c1 = w + 4;
    const int srow0 = c0 * 16 + (lane >> 2);
    const int srow1 = c1 * 16 + (lane >> 2);
    const int scol = (lane & 3) * 8;

    for (int k0 = 0; k0 < 1024; k0 += 32) {
        gload_lds16(A + (size_t)(m0 + srow0) * 1024 + k0 + scol, &Al[c0 * 512]);
        gload_lds16(A + (size_t)(m0 + srow1) * 1024 + k0 + scol, &Al[c1 * 512]);
        gload_lds16(B + (size_t)(n0 + srow0) * 1024 + k0 + scol, &Bl[c0 * 512]);
        gload_lds16(B + (size_t)(n0 + srow1) * 1024 + k0 + scol, &Bl[c1 * 512]);
        __syncthreads();
        f16x8 af[4], bf[4];
        #pragma unroll
        for (int i = 0; i < 4; ++i) {
            af[i] = *(const f16x8*)&Al[(wm * 64 + i * 16 + l15) * 32 + lh * 8];
            bf[i] = *(const f16x8*)&Bl[(wn * 64 + i * 16 + l15) * 32 + lh * 8];
        }
        #pragma unroll
        for (int i = 0; i < 4; ++i)
            #pragma unroll
            for (int j = 0; j < 4; ++j)
                acc[i][j] = MFMA16x32(af[i], bf[j], acc[i][j]);
        __syncthreads();
    }

    const int seg = n0 >> 10;
    const float* bias = (seg == 0) ? bq : (seg == 1) ? bk : bv;
    f16* dst = (seg == 0) ? q_sp : (seg == 1) ? k_sp : v_sp;
    const float scale = (seg == 0) ? 0.18033688011112042f : 1.0f;  // 0.125*log2(e)

    #pragma unroll
    for (int j = 0; j < 4; ++j) {
        const int n = n0 + wn * 64 + j * 16 + l15;
        const int e = n & 1023, hh = e >> 6, d = e & 63;
        const float bsv = bias[e];
        #pragma unroll
        for (int i = 0; i < 4; ++i) {
            #pragma unroll
            for (int r = 0; r < 4; ++r) {
                const int m = m0 + wm * 64 + i * 16 + lh * 4 + r;
                const int t = m >> 2, bb = m & 3;
                dst[((size_t)(bb * 16 + hh) * 2048 + t) * 64 + d] =
                    (f16)((acc[i][j][r] + bsv) * scale);
            }
        }
    }
}

// ---------------- V pack: [BH][T][HD] -> B-fragment order for 16x16x16 MFMA ----
// Vf[bh][nt][lane][dt][r] = V[nt*16 + (lane>>4)*4 + r][dt*16 + (lane&15)]
__global__ __launch_bounds__(256)
void vpack(const f16* __restrict__ v_sp, f16* __restrict__ vf_) {
    __shared__ f16 L[16 * 64];
    const int nt = blockIdx.x, bh = blockIdx.y;
    const int tid = threadIdx.x;
    const f16* src = v_sp + ((size_t)bh * 2048 + nt * 16) * 64;
    if (tid < 128)
        *(f16x8*)&L[tid * 8] = *(const f16x8*)&src[tid * 8];
    __syncthreads();
    const int lane = tid >> 2, dt = tid & 3;
    const int l15 = lane & 15, lh = lane >> 4;
    f16x4 o;
    #pragma unroll
    for (int r = 0; r < 4; ++r) o[r] = L[(lh * 4 + r) * 64 + dt * 16 + l15];
    *(f16x4*)&vf_[((size_t)bh * 128 + nt) * 1024 + tid * 4] = o;
}

// ---------------- fused attention ----------------
// grid (128 q-tiles of 16 rows, 4 batch) = 512 blocks; 1024 thr = 16 waves,
// each wave owns a 128-key strip. A single 1024-thr block forces 4 waves/SIMD
// residency (R6 evidence: 48% occupancy); the slim QBLK=16 single-group body
// (~92 regs true need: avgv 16 + t 16 + acc 16 + Q 8 + in-flight 16 + addr)
// fits the forced <=128 total WITHOUT scratch spill (R6's failure mode).
__global__ __launch_bounds__(1024, 1)
void attn_kernel(const f16* __restrict__ q_s, const f16* __restrict__ k_s,
                 const f16* __restrict__ v_f, f16* __restrict__ ctx,
                 float* __restrict__ avg_out)
{
    __shared__ float Oacc[2][1024];      // [buf][qrow*64+d] = 8 KB
    __shared__ float sumL[16][16];

    const int tid = threadIdx.x;
    const int lane = tid & 63;
    const int w = tid >> 6;          // key-strip 0..15 (128 keys each)
    const int b = blockIdx.y;
    const int t0 = blockIdx.x * 16;
    const int l15 = lane & 15, lh = lane >> 4;

    f16x4 avgv[8] = {};              // normalized attn sums, per-lane (q=l15, 32 keys)

    Oacc[0][tid & 1023] = 0.f;
    Oacc[1][tid & 1023] = 0.f;
    __syncthreads();

    for (int h = 0; h < 16; ++h) {
        const f16* Qh  = q_s + ((size_t)(b * 16 + h) * 2048 + t0) * 64;
        const f16* Kh  = k_s + (size_t)(b * 16 + h) * 2048 * 64 + (size_t)w * 128 * 64;
        const f16* Vfh = v_f + (size_t)(b * 16 + h) * 131072 + (size_t)w * 8 * 1024;

        const f16x8 qa0 = *(const f16x8*)(Qh + l15 * 64 + lh * 8);
        const f16x8 qa1 = *(const f16x8*)(Qh + l15 * 64 + 32 + lh * 8);

        // ---- S^T strip in regs + exp2 (no max: range-safe in f16) ----
        f16x4 t[8];
        float rsum = 0.f;
        #pragma unroll
        for (int nt = 0; nt < 8; ++nt) {
            const f16* kp = Kh + (size_t)(nt * 16 + l15) * 64 + lh * 8;
            const f16x8 kf0 = *(const f16x8*)(kp);
            const f16x8 kf1 = *(const f16x8*)(kp + 32);
            f32x4 s = {0.f, 0.f, 0.f, 0.f};
            s = MFMA16x32(kf0, qa0, s);   // swapped: D[key][q]
            s = MFMA16x32(kf1, qa1, s);
            f16x4 tv;
            #pragma unroll
            for (int r = 0; r < 4; ++r) {
                const float e = __builtin_amdgcn_exp2f(s[r]);
                rsum += e;
                tv[r] = (f16)e;
            }
            t[nt] = tv;
        }
        // combine the 4 lh-lanes holding the same q=l15
        rsum += __shfl_xor(rsum, 16);
        rsum += __shfl_xor(rsum, 32);
        if (lane < 16) sumL[w][lane] = rsum;
        __syncthreads();                 // bar1: sums ready; prev ctx reads done

        // zero the other O buffer for the next head
        Oacc[(h + 1) & 1][tid & 1023] = 0.f;

        float tot = 0.f;
        #pragma unroll
        for (int ww = 0; ww < 16; ++ww) tot += sumL[ww][l15];
        const f16 hinv = (f16)(1.f / tot);
        f16x4 hv; hv[0] = hinv; hv[1] = hinv; hv[2] = hinv; hv[3] = hinv;

        // ---- PV (16x16x16, A = normalized t[nt]) + avg accumulate ----
        f32x4 o0 = {}, o1 = {}, o2 = {}, o3 = {};
        #pragma unroll
        for (int nt = 0; nt < 8; ++nt) {
            const f16x4 tn = t[nt] * hv;
            avgv[nt] += tn;
            const f16* vp = Vfh + nt * 1024 + lane * 16;
            const f16x8 vab = *(const f16x8*)(vp);
            const f16x8 vcd = *(const f16x8*)(vp + 8);
            const f16x4 va = __builtin_shufflevector(vab, vab, 0, 1, 2, 3);
            const f16x4 vb = __builtin_shufflevector(vab, vab, 4, 5, 6, 7);
            const f16x4 vc = __builtin_shufflevector(vcd, vcd, 0, 1, 2, 3);
            const f16x4 vd = __builtin_shufflevector(vcd, vcd, 4, 5, 6, 7);
            o0 = MFMA16x16(tn, va, o0);
            o1 = MFMA16x16(tn, vb, o1);
            o2 = MFMA16x16(tn, vc, o2);
            o3 = MFMA16x16(tn, vd, o3);
        }
        float* Ob = &Oacc[h & 1][0];
        #pragma unroll
        for (int r = 0; r < 4; ++r) {
            const int rowb = (lh * 4 + r) * 64;
            atomicAdd(&Ob[rowb +      l15], o0[r]);
            atomicAdd(&Ob[rowb + 16 + l15], o1[r]);
            atomicAdd(&Ob[rowb + 32 + l15], o2[r]);
            atomicAdd(&Ob[rowb + 48 + l15], o3[r]);
        }
        __syncthreads();                 // bar2: Oacc complete

        {   // ctx write: 1024 threads for 16 rows x 64 dims
            const int idx = tid & 1023;
            const int q = idx >> 6, d = idx & 63;
            ctx[((size_t)(t0 + q) * 4 + b) * 1024 + h * 64 + d] = (f16)Ob[idx];
        }
    }

    // ---- write avg_attn: lane owns (q=l15, keys w*128 + nt*16 + lh*4 + r) ----
    const float s16 = 1.f / 16.f;
    float* ao = avg_out + ((size_t)b * 2048 + t0 + l15) * 2048 + w * 128 + lh * 4;
    #pragma unroll
    for (int nt = 0; nt < 8; ++nt) {
        float4 v;
        v.x = (float)avgv[nt][0] * s16; v.y = (float)avgv[nt][1] * s16;
        v.z = (float)avgv[nt][2] * s16; v.w = (float)avgv[nt][3] * s16;
        *(float4*)(ao + nt * 16) = v;
    }
}

// ---------------- output projection GEMM ----------------
__global__ __launch_bounds__(256, 3)
void gemm_out(const f16* __restrict__ A, const f16* __restrict__ B,
              const float* __restrict__ bo, float* __restrict__ out)
{
    __shared__ f16 Al[128 * 32];
    __shared__ f16 Bl[128 * 32];
    const int tid = threadIdx.x, lane = tid & 63, w = tid >> 6;
    const int wm = w >> 1, wn = w & 1;
    const int m0 = blockIdx.y * 128, n0 = blockIdx.x * 128;
    const int l15 = lane & 15, lh = lane >> 4;

    f32x4 acc[4][4] = {};
    const int c0 = w, c1 = w + 4;
    const int srow0 = c0 * 16 + (lane >> 2);
    const int srow1 = c1 * 16 + (lane >> 2);
    const int scol = (lane & 3) * 8;

    for (int k0 = 0; k0 < 1024; k0 += 32) {
        gload_lds16(A + (size_t)(m0 + srow0) * 1024 + k0 + scol, &Al[c0 * 512]);
        gload_lds16(A + (size_t)(m0 + srow1) * 1024 + k0 + scol, &Al[c1 * 512]);
        gload_lds16(B + (size_t)(n0 + srow0) * 1024 + k0 + scol, &Bl[c0 * 512]);
        gload_lds16(B + (size_t)(n0 + srow1) * 1024 + k0 + scol, &Bl[c1 * 512]);
        __syncthreads();
        f16x8 af[4], bf[4];
        #pragma unroll
        for (int i = 0; i < 4; ++i) {
            af[i] = *(const f16x8*)&Al[(wm * 64 + i * 16 + l15) * 32 + lh * 8];
            bf[i] = *(const f16x8*)&Bl[(wn * 64 + i * 16 + l15) * 32 + lh * 8];
        }
        #pragma unroll
        for (int i = 0; i < 4; ++i)
            #pragma unroll
            for (int j = 0; j < 4; ++j)
                acc[i][j] = MFMA16x32(af[i], bf[j], acc[i][j]);
        __syncthreads();
    }

    #pragma unroll
    for (int j = 0; j < 4; ++j) {
        const int n = n0 + wn * 64 + j * 16 + l15;
        const float bsv = bo[n];
        #pragma unroll
        for (int i = 0; i < 4; ++i) {
            #pragma unroll
            for (int r = 0; r < 4; ++r) {
                const int m = m0 + wm * 64 + i * 16 + lh * 4 + r;
                out[(size_t)m * 1024 + n] = acc[i][j][r] + bsv;
            }
        }
    }
}

extern "C" void kernel_launch(void* const* d_in, const int* in_sizes, int n_in,
                              void* d_out, int out_size, void* d_ws, size_t ws_size,
                              hipStream_t stream) {
    const float* query = (const float*)d_in[0];
    const float* wq = (const float*)d_in[1];
    const float* bq = (const float*)d_in[2];
    const float* wk = (const float*)d_in[3];
    const float* bk = (const float*)d_in[4];
    const float* wv = (const float*)d_in[5];
    const float* bv = (const float*)d_in[6];
    const float* wo = (const float*)d_in[7];
    const float* bo = (const float*)d_in[8];
    float* out = (float*)d_out;

    f16* wsh  = (f16*)d_ws;
    f16* Xb   = wsh;                          // 8M  (query f16; later aliased as ctx)
    f16* Wqkv = wsh + (8u << 20);             // 3M
    f16* Wo   = wsh + (11u << 20);            // 1M
    f16* q_sp = wsh + (12u << 20);            // 8M  [B,H,T,HD]
    f16* k_sp = wsh + (20u << 20);            // 8M
    f16* v_sp = wsh + (28u << 20);            // 8M
    f16* v_f  = wsh + (36u << 20);            // 8M  packed B-fragments
    f16* ctx  = Xb;

    cvt_f32_f16<<<4096, 256, 0, stream>>>(query, Xb, 1048576);
    cvt_f32_f16<<<512, 256, 0, stream>>>(wq, Wqkv, 131072);
    cvt_f32_f16<<<512, 256, 0, stream>>>(wk, Wqkv + (1u << 20), 131072);
    cvt_f32_f16<<<512, 256, 0, stream>>>(wv, Wqkv + (2u << 20), 131072);
    cvt_f32_f16<<<512, 256, 0, stream>>>(wo, Wo, 131072);

    gemm_qkv<<<dim3(24, 64), 256, 0, stream>>>(Xb, Wqkv, bq, bk, bv, q_sp, k_sp, v_sp);
    vpack<<<dim3(128, 64), 256, 0, stream>>>(v_sp, v_f);
    attn_kernel<<<dim3(128, 4), 1024, 0, stream>>>(q_sp, k_sp, v_f, ctx,
                                                   out + 8388608 /* avg_attn */);
    gemm_out<<<dim3(8, 64), 256, 0, stream>>>(ctx, Wo, bo, out);
}

// Round 9
// 761.720 us; speedup vs baseline: 1.5083x; 1.5083x over previous
//
#include <hip/hip_runtime.h>
#include <cstdint>
#include <cstddef>

typedef _Float16 f16;
typedef f16   f16x4 __attribute__((ext_vector_type(4)));
typedef f16   f16x8 __attribute__((ext_vector_type(8)));
typedef float f32x4 __attribute__((ext_vector_type(4)));

#define MFMA16x32(a, b, c) __builtin_amdgcn_mfma_f32_16x16x32_f16((a), (b), (c), 0, 0, 0)
#define MFMA16x16(a, b, c) __builtin_amdgcn_mfma_f32_16x16x16f16((a), (b), (c), 0, 0, 0)

// async global->LDS, 16B per lane; lds base must be wave-uniform
__device__ __forceinline__ void gload_lds16(const void* g, void* l) {
    __builtin_amdgcn_global_load_lds(
        (const __attribute__((address_space(1))) unsigned int*)g,
        (__attribute__((address_space(3))) unsigned int*)l, 16, 0, 0);
}

// ---------------- prep: f32 -> f16 copy-cast (8 elems/thread) ----------------
__global__ void cvt_f32_f16(const float* __restrict__ in, f16* __restrict__ out, int n8) {
    int i = blockIdx.x * blockDim.x + threadIdx.x;
    if (i >= n8) return;
    const float4 a = ((const float4*)in)[i * 2];
    const float4 b = ((const float4*)in)[i * 2 + 1];
    f16x8 o;
    o[0] = (f16)a.x; o[1] = (f16)a.y; o[2] = (f16)a.z; o[3] = (f16)a.w;
    o[4] = (f16)b.x; o[5] = (f16)b.y; o[6] = (f16)b.z; o[7] = (f16)b.w;
    *(f16x8*)(out + (size_t)i * 8) = o;
}

// ---------------- avg partial reduce: out = (out + (f32)s0) / 16 ----------------
__global__ void avg_reduce(const f16* __restrict__ s0, float* __restrict__ out, int n8) {
    int i = blockIdx.x * blockDim.x + threadIdx.x;
    if (i >= n8) return;
    const f16x8 s = *(const f16x8*)(s0 + (size_t)i * 8);
    float4 a = ((const float4*)out)[i * 2];
    float4 b = ((const float4*)out)[i * 2 + 1];
    const float k = 1.f / 16.f;
    a.x = (a.x + (float)s[0]) * k; a.y = (a.y + (float)s[1]) * k;
    a.z = (a.z + (float)s[2]) * k; a.w = (a.w + (float)s[3]) * k;
    b.x = (b.x + (float)s[4]) * k; b.y = (b.y + (float)s[5]) * k;
    b.z = (b.z + (float)s[6]) * k; b.w = (b.w + (float)s[7]) * k;
    ((float4*)out)[i * 2] = a;
    ((float4*)out)[i * 2 + 1] = b;
}

// ---------------- QKV projection GEMM ----------------
// q epilogue scale = 0.125 * log2(e): scores then use exp2 directly.
__global__ __launch_bounds__(256, 3)
void gemm_qkv(const f16* __restrict__ A, const f16* __restrict__ B,
              const float* __restrict__ bq, const float* __restrict__ bk,
              const float* __restrict__ bv,
              f16* __restrict__ q_sp, f16* __restrict__ k_sp, f16* __restrict__ v_sp)
{
    __shared__ f16 Al[128 * 32];
    __shared__ f16 Bl[128 * 32];
    const int tid = threadIdx.x, lane = tid & 63, w = tid >> 6;
    const int wm = w >> 1, wn = w & 1;
    const int m0 = blockIdx.y * 128, n0 = blockIdx.x * 128;
    const int l15 = lane & 15, lh = lane >> 4;

    f32x4 acc[4][4] = {};

    const int c0 = w, c1 = w + 4;
    const int srow0 = c0 * 16 + (lane >> 2);
    const int srow1 = c1 * 16 + (lane >> 2);
    const int scol = (lane & 3) * 8;

    for (int k0 = 0; k0 < 1024; k0 += 32) {
        gload_lds16(A + (size_t)(m0 + srow0) * 1024 + k0 + scol, &Al[c0 * 512]);
        gload_lds16(A + (size_t)(m0 + srow1) * 1024 + k0 + scol, &Al[c1 * 512]);
        gload_lds16(B + (size_t)(n0 + srow0) * 1024 + k0 + scol, &Bl[c0 * 512]);
        gload_lds16(B + (size_t)(n0 + srow1) * 1024 + k0 + scol, &Bl[c1 * 512]);
        __syncthreads();
        f16x8 af[4], bf[4];
        #pragma unroll
        for (int i = 0; i < 4; ++i) {
            af[i] = *(const f16x8*)&Al[(wm * 64 + i * 16 + l15) * 32 + lh * 8];
            bf[i] = *(const f16x8*)&Bl[(wn * 64 + i * 16 + l15) * 32 + lh * 8];
        }
        #pragma unroll
        for (int i = 0; i < 4; ++i)
            #pragma unroll
            for (int j = 0; j < 4; ++j)
                acc[i][j] = MFMA16x32(af[i], bf[j], acc[i][j]);
        __syncthreads();
    }

    const int seg = n0 >> 10;
    const float* bias = (seg == 0) ? bq : (seg == 1) ? bk : bv;
    f16* dst = (seg == 0) ? q_sp : (seg == 1) ? k_sp : v_sp;
    const float scale = (seg == 0) ? 0.18033688011112042f : 1.0f;  // 0.125*log2(e)

    #pragma unroll
    for (int j = 0; j < 4; ++j) {
        const int n = n0 + wn * 64 + j * 16 + l15;
        const int e = n & 1023, hh = e >> 6, d = e & 63;
        const float bsv = bias[e];
        #pragma unroll
        for (int i = 0; i < 4; ++i) {
            #pragma unroll
            for (int r = 0; r < 4; ++r) {
                const int m = m0 + wm * 64 + i * 16 + lh * 4 + r;
                const int t = m >> 2, bb = m & 3;
                dst[((size_t)(bb * 16 + hh) * 2048 + t) * 64 + d] =
                    (f16)((acc[i][j][r] + bsv) * scale);
            }
        }
    }
}

// ---------------- V pack: [BH][T][HD] -> B-fragment order for 16x16x16 MFMA ----
// Vf[bh][nt][lane][dt][r] = V[nt*16 + (lane>>4)*4 + r][dt*16 + (lane&15)]
__global__ __launch_bounds__(256)
void vpack(const f16* __restrict__ v_sp, f16* __restrict__ vf_) {
    __shared__ f16 L[16 * 64];
    const int nt = blockIdx.x, bh = blockIdx.y;
    const int tid = threadIdx.x;
    const f16* src = v_sp + ((size_t)bh * 2048 + nt * 16) * 64;
    if (tid < 128)
        *(f16x8*)&L[tid * 8] = *(const f16x8*)&src[tid * 8];
    __syncthreads();
    const int lane = tid >> 2, dt = tid & 3;
    const int l15 = lane & 15, lh = lane >> 4;
    f16x4 o;
    #pragma unroll
    for (int r = 0; r < 4; ++r) o[r] = L[(lh * 4 + r) * 64 + dt * 16 + l15];
    *(f16x4*)&vf_[((size_t)bh * 128 + nt) * 1024 + tid * 4] = o;
}

// ---------------- fused attention ----------------
// 1D grid of 512, 512 thr (8 waves = 8 key-strips of 256). XCD-locality
// decode: group g = bid & 7 selects (batch, head-half); hardware round-robin
// maps consecutive bids to XCDs, so all 64 q-tile blocks of group g land on
// XCD g. Per-group K + Vf = 4 MB = one XCD's L2 -> K/V re-reads become L2
// hits instead of thrashing the XCD<->L3 fabric (R8 diagnosis: dur tracks
// K/V L2-fill traffic at ~3.4 TB/s).
__global__ __launch_bounds__(512, 2)
void attn_kernel(const f16* __restrict__ q_s, const f16* __restrict__ k_s,
                 const f16* __restrict__ v_f, f16* __restrict__ ctx,
                 float* __restrict__ avg_out, f16* __restrict__ pavg)
{
    __shared__ float Oacc[2][2][1024];   // [buf][group][qrow*64+d] = 16 KB
    __shared__ float sumL[8][2][16];

    const int tid = threadIdx.x;
    const int lane = tid & 63;
    const int w = tid >> 6;          // key-strip 0..7
    const int g = blockIdx.x & 7;    // XCD-locality group
    const int b = g & 3;
    const int hz = g >> 2;           // head half: heads hz*8 .. hz*8+7
    const int t0 = (blockIdx.x >> 3) * 32;
    const int l15 = lane & 15, lh = lane >> 4;

    f16x4 avgv0[16] = {}, avgv1[16] = {};

    {   // zero both O buffers
        float* Oz = &Oacc[0][0][0];
        #pragma unroll
        for (int jj = 0; jj < 8; ++jj) Oz[tid + jj * 512] = 0.f;
    }
    __syncthreads();

    for (int i = 0; i < 8; ++i) {
        const int h = hz * 8 + i;
        const f16* Qh  = q_s + ((size_t)(b * 16 + h) * 2048 + t0) * 64;
        const f16* Kh  = k_s + (size_t)(b * 16 + h) * 2048 * 64 + (size_t)w * 256 * 64;
        const f16* Vfh = v_f + (size_t)(b * 16 + h) * 131072 + (size_t)w * 16 * 1024;

        // Q fragments for both 16-row groups
        const f16x8 qa0 = *(const f16x8*)(Qh + l15 * 64 + lh * 8);
        const f16x8 qa1 = *(const f16x8*)(Qh + l15 * 64 + 32 + lh * 8);
        const f16x8 qb0 = *(const f16x8*)(Qh + (16 + l15) * 64 + lh * 8);
        const f16x8 qb1 = *(const f16x8*)(Qh + (16 + l15) * 64 + 32 + lh * 8);

        // ---- S^T strips in regs + exp2 (no max: range-safe in f16) ----
        f16x4 tA[16], tB[16];
        float rsA = 0.f, rsB = 0.f;
        #pragma unroll
        for (int nt = 0; nt < 16; ++nt) {
            const f16* kp = Kh + (size_t)(nt * 16 + l15) * 64 + lh * 8;
            const f16x8 kf0 = *(const f16x8*)(kp);
            const f16x8 kf1 = *(const f16x8*)(kp + 32);
            f32x4 sA = {0.f, 0.f, 0.f, 0.f}, sB = {0.f, 0.f, 0.f, 0.f};
            sA = MFMA16x32(kf0, qa0, sA); sA = MFMA16x32(kf1, qa1, sA);
            sB = MFMA16x32(kf0, qb0, sB); sB = MFMA16x32(kf1, qb1, sB);
            f16x4 ta, tb;
            #pragma unroll
            for (int r = 0; r < 4; ++r) {
                const float eA = __builtin_amdgcn_exp2f(sA[r]);
                const float eB = __builtin_amdgcn_exp2f(sB[r]);
                rsA += eA; rsB += eB;
                ta[r] = (f16)eA; tb[r] = (f16)eB;
            }
            tA[nt] = ta; tB[nt] = tb;
        }
        // combine the 4 lh-lanes holding the same q=l15
        rsA += __shfl_xor(rsA, 16); rsA += __shfl_xor(rsA, 32);
        rsB += __shfl_xor(rsB, 16); rsB += __shfl_xor(rsB, 32);
        if (lane < 16) { sumL[w][0][lane] = rsA; sumL[w][1][lane] = rsB; }
        __syncthreads();                 // bar1: sums ready; prev ctx reads done

        // zero the other O buffer for the next head
        {
            float* Oz = &Oacc[(i + 1) & 1][0][0];
            #pragma unroll
            for (int jj = 0; jj < 4; ++jj) Oz[tid + jj * 512] = 0.f;
        }

        float totA = 0.f, totB = 0.f;
        #pragma unroll
        for (int ww = 0; ww < 8; ++ww) {
            totA += sumL[ww][0][l15];
            totB += sumL[ww][1][l15];
        }
        const f16 hiA = (f16)(1.f / totA), hiB = (f16)(1.f / totB);
        f16x4 hvA; hvA[0] = hiA; hvA[1] = hiA; hvA[2] = hiA; hvA[3] = hiA;
        f16x4 hvB; hvB[0] = hiB; hvB[1] = hiB; hvB[2] = hiB; hvB[3] = hiB;

        // ---- PV (shared V loads feed both groups) + avg accumulate ----
        f32x4 a0 = {}, a1 = {}, a2 = {}, a3 = {};
        f32x4 b0 = {}, b1 = {}, b2 = {}, b3 = {};
        #pragma unroll
        for (int nt = 0; nt < 16; ++nt) {
            const f16x4 tnA = tA[nt] * hvA;
            const f16x4 tnB = tB[nt] * hvB;
            avgv0[nt] += tnA;
            avgv1[nt] += tnB;
            const f16* vp = Vfh + nt * 1024 + lane * 16;
            const f16x8 vab = *(const f16x8*)(vp);
            const f16x8 vcd = *(const f16x8*)(vp + 8);
            const f16x4 va = __builtin_shufflevector(vab, vab, 0, 1, 2, 3);
            const f16x4 vb = __builtin_shufflevector(vab, vab, 4, 5, 6, 7);
            const f16x4 vc = __builtin_shufflevector(vcd, vcd, 0, 1, 2, 3);
            const f16x4 vd = __builtin_shufflevector(vcd, vcd, 4, 5, 6, 7);
            a0 = MFMA16x16(tnA, va, a0); a1 = MFMA16x16(tnA, vb, a1);
            a2 = MFMA16x16(tnA, vc, a2); a3 = MFMA16x16(tnA, vd, a3);
            b0 = MFMA16x16(tnB, va, b0); b1 = MFMA16x16(tnB, vb, b1);
            b2 = MFMA16x16(tnB, vc, b2); b3 = MFMA16x16(tnB, vd, b3);
        }
        float* OA = &Oacc[i & 1][0][0];
        float* OB = &Oacc[i & 1][1][0];
        #pragma unroll
        for (int r = 0; r < 4; ++r) {
            const int rowb = (lh * 4 + r) * 64;
            atomicAdd(&OA[rowb +      l15], a0[r]);
            atomicAdd(&OA[rowb + 16 + l15], a1[r]);
            atomicAdd(&OA[rowb + 32 + l15], a2[r]);
            atomicAdd(&OA[rowb + 48 + l15], a3[r]);
            atomicAdd(&OB[rowb +      l15], b0[r]);
            atomicAdd(&OB[rowb + 16 + l15], b1[r]);
            atomicAdd(&OB[rowb + 32 + l15], b2[r]);
            atomicAdd(&OB[rowb + 48 + l15], b3[r]);
        }
        __syncthreads();                 // bar2: Oacc complete

        #pragma unroll
        for (int jj = 0; jj < 4; ++jj) {
            const int idx = tid + jj * 512;        // 0..2047
            const int gg = idx >> 10, rem = idx & 1023;
            const int q = rem >> 6, d = rem & 63;
            ctx[((size_t)(t0 + gg * 16 + q) * 4 + b) * 1024 + h * 64 + d] =
                (f16)Oacc[i & 1][gg][rem];
        }
    }

    // ---- write avg partial: lane owns (q=l15 [+16], keys w*256 + nt*16 + lh*4+r) ----
    // unscaled sums over this z-half's 8 heads. z0 -> f16 ws slice, z1 -> raw f32.
    if (hz == 0) {
        f16* ao0 = pavg + ((size_t)b * 2048 + t0 + l15) * 2048 + w * 256 + lh * 4;
        f16* ao1 = pavg + ((size_t)b * 2048 + t0 + 16 + l15) * 2048 + w * 256 + lh * 4;
        #pragma unroll
        for (int nt = 0; nt < 16; ++nt) {
            *(f16x4*)(ao0 + nt * 16) = avgv0[nt];
            *(f16x4*)(ao1 + nt * 16) = avgv1[nt];
        }
    } else {
        float* ao0 = avg_out + ((size_t)b * 2048 + t0 + l15) * 2048 + w * 256 + lh * 4;
        float* ao1 = avg_out + ((size_t)b * 2048 + t0 + 16 + l15) * 2048 + w * 256 + lh * 4;
        #pragma unroll
        for (int nt = 0; nt < 16; ++nt) {
            float4 v0, v1;
            v0.x = (float)avgv0[nt][0]; v0.y = (float)avgv0[nt][1];
            v0.z = (float)avgv0[nt][2]; v0.w = (float)avgv0[nt][3];
            v1.x = (float)avgv1[nt][0]; v1.y = (float)avgv1[nt][1];
            v1.z = (float)avgv1[nt][2]; v1.w = (float)avgv1[nt][3];
            *(float4*)(ao0 + nt * 16) = v0;
            *(float4*)(ao1 + nt * 16) = v1;
        }
    }
}

// ---------------- output projection GEMM ----------------
__global__ __launch_bounds__(256, 3)
void gemm_out(const f16* __restrict__ A, const f16* __restrict__ B,
              const float* __restrict__ bo, float* __restrict__ out)
{
    __shared__ f16 Al[128 * 32];
    __shared__ f16 Bl[128 * 32];
    const int tid = threadIdx.x, lane = tid & 63, w = tid >> 6;
    const int wm = w >> 1, wn = w & 1;
    const int m0 = blockIdx.y * 128, n0 = blockIdx.x * 128;
    const int l15 = lane & 15, lh = lane >> 4;

    f32x4 acc[4][4] = {};
    const int c0 = w, c1 = w + 4;
    const int srow0 = c0 * 16 + (lane >> 2);
    const int srow1 = c1 * 16 + (lane >> 2);
    const int scol = (lane & 3) * 8;

    for (int k0 = 0; k0 < 1024; k0 += 32) {
        gload_lds16(A + (size_t)(m0 + srow0) * 1024 + k0 + scol, &Al[c0 * 512]);
        gload_lds16(A + (size_t)(m0 + srow1) * 1024 + k0 + scol, &Al[c1 * 512]);
        gload_lds16(B + (size_t)(n0 + srow0) * 1024 + k0 + scol, &Bl[c0 * 512]);
        gload_lds16(B + (size_t)(n0 + srow1) * 1024 + k0 + scol, &Bl[c1 * 512]);
        __syncthreads();
        f16x8 af[4], bf[4];
        #pragma unroll
        for (int i = 0; i < 4; ++i) {
            af[i] = *(const f16x8*)&Al[(wm * 64 + i * 16 + l15) * 32 + lh * 8];
            bf[i] = *(const f16x8*)&Bl[(wn * 64 + i * 16 + l15) * 32 + lh * 8];
        }
        #pragma unroll
        for (int i = 0; i < 4; ++i)
            #pragma unroll
            for (int j = 0; j < 4; ++j)
                acc[i][j] = MFMA16x32(af[i], bf[j], acc[i][j]);
        __syncthreads();
    }

    #pragma unroll
    for (int j = 0; j < 4; ++j) {
        const int n = n0 + wn * 64 + j * 16 + l15;
        const float bsv = bo[n];
        #pragma unroll
        for (int i = 0; i < 4; ++i) {
            #pragma unroll
            for (int r = 0; r < 4; ++r) {
                const int m = m0 + wm * 64 + i * 16 + lh * 4 + r;
                out[(size_t)m * 1024 + n] = acc[i][j][r] + bsv;
            }
        }
    }
}

extern "C" void kernel_launch(void* const* d_in, const int* in_sizes, int n_in,
                              void* d_out, int out_size, void* d_ws, size_t ws_size,
                              hipStream_t stream) {
    const float* query = (const float*)d_in[0];
    const float* wq = (const float*)d_in[1];
    const float* bq = (const float*)d_in[2];
    const float* wk = (const float*)d_in[3];
    const float* bk = (const float*)d_in[4];
    const float* wv = (const float*)d_in[5];
    const float* bv = (const float*)d_in[6];
    const float* wo = (const float*)d_in[7];
    const float* bo = (const float*)d_in[8];
    float* out = (float*)d_out;

    f16* wsh  = (f16*)d_ws;
    f16* Xb   = wsh;                          // 8M  (query f16; later aliased as ctx)
    f16* Wqkv = wsh + (8u << 20);             // 3M
    f16* Wo   = wsh + (11u << 20);            // 1M
    f16* q_sp = wsh + (12u << 20);            // 8M  [B,H,T,HD]
    f16* k_sp = wsh + (20u << 20);            // 8M
    f16* v_sp = wsh + (28u << 20);            // 8M
    f16* v_f  = wsh + (36u << 20);            // 8M  packed B-fragments
    f16* pavg = wsh + (44u << 20);            // 16M f16 = 32MB avg partial (z0)
    f16* ctx  = Xb;

    cvt_f32_f16<<<4096, 256, 0, stream>>>(query, Xb, 1048576);
    cvt_f32_f16<<<512, 256, 0, stream>>>(wq, Wqkv, 131072);
    cvt_f32_f16<<<512, 256, 0, stream>>>(wk, Wqkv + (1u << 20), 131072);
    cvt_f32_f16<<<512, 256, 0, stream>>>(wv, Wqkv + (2u << 20), 131072);
    cvt_f32_f16<<<512, 256, 0, stream>>>(wo, Wo, 131072);

    gemm_qkv<<<dim3(24, 64), 256, 0, stream>>>(Xb, Wqkv, bq, bk, bv, q_sp, k_sp, v_sp);
    vpack<<<dim3(128, 64), 256, 0, stream>>>(v_sp, v_f);
    attn_kernel<<<512, 512, 0, stream>>>(q_sp, k_sp, v_f, ctx,
                                         out + 8388608 /* avg_attn */, pavg);
    avg_reduce<<<8192, 256, 0, stream>>>(pavg, out + 8388608, 2097152);
    gemm_out<<<dim3(8, 64), 256, 0, stream>>>(ctx, Wo, bo, out);
}